// Round 3
// baseline (652.420 us; speedup 1.0000x reference)
//
#include <hip/hip_runtime.h>
#include <hip/hip_fp16.h>

// ForwardDeformer (B=4, N=250000, J=55, vol [55,16,64,64]).
// R1: pre-blend voxel grid with matrices (linearity) -> per-voxel 4x4 mats.
// R4: global compaction -> scattered partial-line writes -> RMW. Reverted.
// R5: team=point lane=batch, 111.6us — floor was masked-path DS storm
//     (~280 ds_read_b128/lane) serializing on the CU's single DS pipe,
//     paid by EVERY wave (mixed-mask teams).
// R6: block partition + butterfly: VALU 38->30% but DS storm kept, dur flat.
// R7: b=blockIdx.y: masked path went SGPR (good) but shared-per-point reads
//     (lbsw) multiplied 4x across XCDs (+200MB FETCH) and 4 independent
//     permuted scatters broke write-combining (+262MB WRITE). 276us.
// R8: batch = WAVE index within the block (b=readfirstlane(tx>>6)):
//     - matrices via s_load (SGPR operands): masked body = pure VALU,
//       4 pipes/CU instead of 1 DS pipe. ZERO LDS, ZERO barriers.
//     - same block covers same 64 points for all 4 b -> lbsw/mask reuse in L1.
//     - per-wave mask partition via ballot + one ds_permute (branch-uniform
//       waves); writes stay in per-wave 64-pt windows -> L2 write-combines.
//     - unmasked: per-thread 64B tab-entry gather (1 line/corner).

#define JNT 55
#define VD  16
#define VH  64
#define VW  64
#define NVOX (VD * VH * VW)   // 65536

// ---------------------------------------------------------------------------
// Pre-pass: tab[(b*NVOX+v)] = 64B entry { half Mi[16], half Mv_b[16] }.
// ---------------------------------------------------------------------------
__global__ __launch_bounds__(256, 2) void build_tab_k(
    const float* __restrict__ vol, const float* __restrict__ tfs,
    const float* __restrict__ tfs_inv, __half* __restrict__ tab)
{
    int v = blockIdx.x * 256 + threadIdx.x;
    int b = blockIdx.y;
    if (v >= NVOX) return;
    float w[JNT];
#pragma unroll
    for (int j = 0; j < JNT; ++j) w[j] = vol[j * NVOX + v];

    float Mi[16], Mv[16];
#pragma unroll
    for (int i = 0; i < 16; ++i) { Mi[i] = 0.f; Mv[i] = 0.f; }
    const float* tb = tfs + (size_t)b * JNT * 16;
#pragma unroll
    for (int j = 0; j < JNT; ++j) {
        float wj = w[j];
#pragma unroll
        for (int i = 0; i < 16; ++i) Mi[i] = fmaf(wj, tfs_inv[j * 16 + i], Mi[i]);
#pragma unroll
        for (int i = 0; i < 16; ++i) Mv[i] = fmaf(wj, tb[j * 16 + i], Mv[i]);
    }
    float h[16];
#pragma unroll
    for (int i = 0; i < 8; ++i)
        h[i] = __builtin_bit_cast(float, __floats2half2_rn(Mi[2*i], Mi[2*i+1]));
#pragma unroll
    for (int i = 0; i < 8; ++i)
        h[8+i] = __builtin_bit_cast(float, __floats2half2_rn(Mv[2*i], Mv[2*i+1]));

    float4* d4 = (float4*)(tab + ((size_t)b * NVOX + v) * 32);
    d4[0] = make_float4(h[0],  h[1],  h[2],  h[3]);
    d4[1] = make_float4(h[4],  h[5],  h[6],  h[7]);
    d4[2] = make_float4(h[8],  h[9],  h[10], h[11]);
    d4[3] = make_float4(h[12], h[13], h[14], h[15]);
}

// Accumulate 8 fp16 values (one float4 of packed half2) into a[0..7].
__device__ __forceinline__ void acc8(float cw, float4 r, float* a)
{
    float rr[4] = {r.x, r.y, r.z, r.w};
#pragma unroll
    for (int kk = 0; kk < 4; ++kk) {
        __half2 h = __builtin_bit_cast(__half2, rr[kk]);
        float2 f = __half22float2(h);
        a[2*kk]     = fmaf(cw, f.x, a[2*kk]);
        a[2*kk + 1] = fmaf(cw, f.y, a[2*kk + 1]);
    }
}

__device__ __forceinline__ void epilogue(
    int b, int n, int N, float x, float y, float z,
    const float* A, const float* Ai,
    const float* __restrict__ shoff, const float* __restrict__ pooff,
    const float* __restrict__ poori,
    float* __restrict__ out_xd, float* __restrict__ out_w)
{
    size_t pid = (size_t)b * N + n;
    size_t p3  = pid * 3;
    size_t n3  = (size_t)n * 3;
    float c0 = Ai[0]*x + Ai[1]*y + Ai[2]*z  + Ai[3];
    float c1 = Ai[4]*x + Ai[5]*y + Ai[6]*z  + Ai[7];
    float c2 = Ai[8]*x + Ai[9]*y + Ai[10]*z + Ai[11];
    float sx = c0 - poori[n3 + 0] + shoff[p3 + 0] + pooff[p3 + 0];
    float sy = c1 - poori[n3 + 1] + shoff[p3 + 1] + pooff[p3 + 1];
    float sz = c2 - poori[n3 + 2] + shoff[p3 + 2] + pooff[p3 + 2];
    out_xd[p3 + 0] = A[0]*sx + A[1]*sy + A[2]*sz  + A[3];
    out_xd[p3 + 1] = A[4]*sx + A[5]*sy + A[6]*sz  + A[7];
    out_xd[p3 + 2] = A[8]*sx + A[9]*sy + A[10]*sz + A[11];

    float4* ow = (float4*)(out_w + pid * 16);
#pragma unroll
    for (int i = 0; i < 4; ++i) {
        float a0 = A[i*4+0], a1 = A[i*4+1], a2 = A[i*4+2], a3 = A[i*4+3];
        float4 r;
        r.x = a0*Ai[0] + a1*Ai[4] + a2*Ai[8]  + a3*Ai[12];
        r.y = a0*Ai[1] + a1*Ai[5] + a2*Ai[9]  + a3*Ai[13];
        r.z = a0*Ai[2] + a1*Ai[6] + a2*Ai[10] + a3*Ai[14];
        r.w = a0*Ai[3] + a1*Ai[7] + a2*Ai[11] + a3*Ai[15];
        ow[i] = r;
    }
}

// ---------------------------------------------------------------------------
// Main kernel: block = 4 waves over the SAME 64-point window; wave w = batch
// w (b = readfirstlane -> SGPR). Per-wave mask partition via ballot +
// ds_permute keeps waves branch-uniform. No LDS, no barriers.
// ---------------------------------------------------------------------------
template <int B>
__global__ __launch_bounds__(256, 8) void main_k(
    const float* __restrict__ xc,
    const float* __restrict__ shoff,
    const float* __restrict__ pooff,
    const float* __restrict__ tfs,        // [B, J, 16]
    const float* __restrict__ tfs_inv,    // [J, 16]
    const float* __restrict__ poori,      // [N, 3]
    const float* __restrict__ lbsw,       // [N, J]
    const int*   __restrict__ mask,       // [N]
    const __half* __restrict__ tab,       // [B, NVOX, 32 halves]
    const float* __restrict__ offk,
    const float* __restrict__ sck,
    float* __restrict__ out_xd,
    float* __restrict__ out_w,
    int N)
{
    int tx = threadIdx.x;
    int ln = tx & 63;
    int b  = __builtin_amdgcn_readfirstlane(tx >> 6);   // wave-uniform batch
    int base = blockIdx.x * 64;

    // ---- per-wave mask partition (masked slots first), no LDS -------------
    int n0 = base + ln;
    bool mm = (n0 < N) && (mask[n0] != 0);
    unsigned long long bal = __ballot(mm);
    int nm = __popcll(bal);
    unsigned long long below = bal & ((1ull << ln) - 1ull);
    int rb = __popcll(below);
    int pos = mm ? rb : (nm + ln - rb);
    // push own lane id to lane 'pos': perm[pos] = ln
    int slot = __builtin_amdgcn_ds_permute(pos << 2, ln);
    int n = base + slot;
    bool m = (ln < nm);            // masked slots sorted first
    if (n >= N) return;            // tail lives at end of unmasked segment

    size_t p3 = ((size_t)b * N + n) * 3;
    float x = xc[p3], y = xc[p3 + 1], z = xc[p3 + 2];

    float A[16], Ai[16];
#pragma unroll
    for (int i = 0; i < 16; ++i) { A[i] = 0.f; Ai[i] = 0.f; }

    if (m) {
        // ---- masked: matrices wave-uniform -> s_load + v_fma(SGPR) --------
        const float* tb  = tfs + (size_t)b * JNT * 16;
        const float* row = lbsw + (size_t)n * JNT;
        for (int j = 0; j < JNT; ++j) {
            float wj = row[j];
#pragma unroll
            for (int i = 0; i < 16; ++i) Ai[i] = fmaf(wj, tfs_inv[j*16+i], Ai[i]);
#pragma unroll
            for (int i = 0; i < 16; ++i) A[i]  = fmaf(wj, tb[j*16+i],      A[i]);
        }
    } else {
        // ---- unmasked: 8-corner gather of own 64B tab entry ---------------
        float px = (x + offk[0]) * sck[0];
        float py = (y + offk[1]) * sck[1];
        float pz = (z + offk[2]) * sck[2];
        float ix = fminf(fmaxf((px + 1.f) * 0.5f * (VW - 1), 0.f), (float)(VW - 1));
        float iy = fminf(fmaxf((py + 1.f) * 0.5f * (VH - 1), 0.f), (float)(VH - 1));
        float iz = fminf(fmaxf((pz + 1.f) * 0.5f * (VD - 1), 0.f), (float)(VD - 1));
        float fx = floorf(ix), fy = floorf(iy), fz = floorf(iz);
        float wx = ix - fx,    wy = iy - fy,    wz = iz - fz;
        int x0 = (int)fx, y0 = (int)fy, z0 = (int)fz;
        int x1 = min(x0 + 1, VW - 1);
        int y1 = min(y0 + 1, VH - 1);
        int z1 = min(z0 + 1, VD - 1);
        float cwx[2] = {1.f - wx, wx};
        float cwy[2] = {1.f - wy, wy};
        float cwz[2] = {1.f - wz, wz};
        int   xs[2] = {x0, x1}, ys[2] = {y0, y1}, zs[2] = {z0, z1};

        const __half* tbb = tab + (size_t)b * NVOX * 32;
#pragma unroll
        for (int c = 0; c < 8; ++c) {
            int cz = c >> 2, cy = (c >> 1) & 1, cx = c & 1;
            int vox = (zs[cz] * VH + ys[cy]) * VW + xs[cx];
            float cw = cwz[cz] * cwy[cy] * cwx[cx];
            const float4* e = (const float4*)(tbb + (size_t)vox * 32);
            float4 e0 = e[0], e1 = e[1], e2 = e[2], e3 = e[3];
            acc8(cw, e0, Ai);
            acc8(cw, e1, Ai + 8);
            acc8(cw, e2, A);
            acc8(cw, e3, A + 8);
        }
    }

    epilogue(b, n, N, x, y, z, A, Ai, shoff, pooff, poori, out_xd, out_w);
}

// ---------------------------------------------------------------------------
// Fallback (ws too small or B != 4): per-thread direct gather from vol.
// ---------------------------------------------------------------------------
__global__ __launch_bounds__(256) void fb_k(
    const float* __restrict__ xc, const float* __restrict__ shoff,
    const float* __restrict__ pooff, const float* __restrict__ tfs,
    const float* __restrict__ tfs_inv, const float* __restrict__ poori,
    const float* __restrict__ lbsw, const int* __restrict__ mask,
    const float* __restrict__ vol, const float* __restrict__ offk,
    const float* __restrict__ sck, float* __restrict__ out_xd,
    float* __restrict__ out_w, int N)
{
    int n = blockIdx.x * 256 + threadIdx.x;
    int b = blockIdx.y;
    if (n >= N) return;
    size_t p3 = ((size_t)b * N + n) * 3;
    float x = xc[p3], y = xc[p3 + 1], z = xc[p3 + 2];
    float A[16], Ai[16];
#pragma unroll
    for (int i = 0; i < 16; ++i) { A[i] = 0.f; Ai[i] = 0.f; }
    const float* tb = tfs + (size_t)b * JNT * 16;

    if (mask[n] != 0) {
        const float* lp = lbsw + (size_t)n * JNT;
        for (int j = 0; j < JNT; ++j) {
            float wj = lp[j];
#pragma unroll
            for (int i = 0; i < 16; ++i) Ai[i] = fmaf(wj, tfs_inv[j*16+i], Ai[i]);
#pragma unroll
            for (int i = 0; i < 16; ++i) A[i]  = fmaf(wj, tb[j*16+i],      A[i]);
        }
    } else {
        float px = (x + offk[0]) * sck[0];
        float py = (y + offk[1]) * sck[1];
        float pz = (z + offk[2]) * sck[2];
        float ix = fminf(fmaxf((px + 1.f) * 0.5f * (VW - 1), 0.f), (float)(VW - 1));
        float iy = fminf(fmaxf((py + 1.f) * 0.5f * (VH - 1), 0.f), (float)(VH - 1));
        float iz = fminf(fmaxf((pz + 1.f) * 0.5f * (VD - 1), 0.f), (float)(VD - 1));
        float fx = floorf(ix), fy = floorf(iy), fz = floorf(iz);
        float wx = ix - fx, wy = iy - fy, wz = iz - fz;
        int x0 = (int)fx, y0 = (int)fy, z0 = (int)fz;
        int x1 = min(x0 + 1, VW - 1);
        int y1 = min(y0 + 1, VH - 1);
        int z1 = min(z0 + 1, VD - 1);
        float w00 = (1.f - wz) * (1.f - wy), w01 = (1.f - wz) * wy;
        float w10 = wz * (1.f - wy),         w11 = wz * wy;
        int o00 = (z0 * VH + y0) * VW, o01 = (z0 * VH + y1) * VW;
        int o10 = (z1 * VH + y0) * VW, o11 = (z1 * VH + y1) * VW;
        for (int j = 0; j < JNT; ++j) {
            const float* vp = vol + (size_t)j * NVOX;
            float v000 = vp[o00 + x0], v001 = vp[o00 + x1];
            float v010 = vp[o01 + x0], v011 = vp[o01 + x1];
            float v100 = vp[o10 + x0], v101 = vp[o10 + x1];
            float v110 = vp[o11 + x0], v111 = vp[o11 + x1];
            float c0 = w00 * v000 + w01 * v010 + w10 * v100 + w11 * v110;
            float c1 = w00 * v001 + w01 * v011 + w10 * v101 + w11 * v111;
            float wj = c0 + wx * (c1 - c0);
#pragma unroll
            for (int i = 0; i < 16; ++i) Ai[i] = fmaf(wj, tfs_inv[j*16+i], Ai[i]);
#pragma unroll
            for (int i = 0; i < 16; ++i) A[i]  = fmaf(wj, tb[j*16+i],      A[i]);
        }
    }
    epilogue(b, n, N, x, y, z, A, Ai, shoff, pooff, poori, out_xd, out_w);
}

extern "C" void kernel_launch(void* const* d_in, const int* in_sizes, int n_in,
                              void* d_out, int out_size, void* d_ws, size_t ws_size,
                              hipStream_t stream)
{
    const float* xc    = (const float*)d_in[0];
    const float* shoff = (const float*)d_in[1];
    const float* pooff = (const float*)d_in[2];
    const float* tfs   = (const float*)d_in[3];
    const float* tfsi  = (const float*)d_in[4];
    const float* poori = (const float*)d_in[5];
    const float* lbsw  = (const float*)d_in[6];
    const int*   mask  = (const int*)d_in[7];
    const float* vol   = (const float*)d_in[8];
    const float* offk  = (const float*)d_in[9];
    const float* sck   = (const float*)d_in[10];

    int N = in_sizes[5] / 3;          // poseoff_ori [1,N,3]
    int B = in_sizes[0] / (3 * N);    // xc [B,N,3]
    float* out_xd = (float*)d_out;
    float* out_w  = (float*)d_out + (size_t)B * N * 3;

    size_t tab_bytes = (size_t)B * NVOX * 32 * sizeof(__half);  // 16.78 MB
    __half* tab = (__half*)d_ws;

    if (B == 4 && ws_size >= tab_bytes) {
        build_tab_k<<<dim3((NVOX + 255) / 256, 4), dim3(256), 0, stream>>>(
            vol, tfs, tfsi, tab);
        main_k<4><<<dim3((N + 63) / 64), dim3(256), 0, stream>>>(
            xc, shoff, pooff, tfs, tfsi, poori, lbsw, mask, tab,
            offk, sck, out_xd, out_w, N);
    } else {
        fb_k<<<dim3((N + 255) / 256, B), dim3(256), 0, stream>>>(
            xc, shoff, pooff, tfs, tfsi, poori, lbsw, mask, vol, offk, sck,
            out_xd, out_w, N);
    }
}

// Round 4
// 471.939 us; speedup vs baseline: 1.3824x; 1.3824x over previous
//
#include <hip/hip_runtime.h>
#include <hip/hip_fp16.h>

// ForwardDeformer (B=4, N=250000, J=55, vol [55,16,64,64]).
// R1: pre-blend voxel grid with matrices (linearity) -> per-voxel 4x4 mats.
// R5: team=point lane=batch, 111.6us — floor was masked-path DS storm
//     (~280 ds_read_b128/lane) serializing on the CU's single DS pipe.
// R6: block partition + butterfly: VALU 38->30% but DS storm kept, dur flat.
// R7: b=blockIdx.y: SGPR matrices (good) but cross-block traffic + partial
//     spill at VGPR=64. 276us.
// R8: batch=wave-index structure (SGPR matrices, no LDS/barriers, per-wave
//     ballot partition, per-thread 64B tab gather) BUT __launch_bounds__(256,8)
//     capped VGPRs at 32 -> A[16]+Ai[16] accumulators SPILLED to scratch ->
//     FETCH/WRITE +430MB symmetric, 484us at 8% VALU. Structure unfalsified.
// R9: same structure, __launch_bounds__(256,4) -> 128-VGPR budget, no spill;
//     float4 lbsw row loads (14 VMEM vs 55).

#define JNT 55
#define VD  16
#define VH  64
#define VW  64
#define NVOX (VD * VH * VW)   // 65536

typedef float f4u __attribute__((ext_vector_type(4), aligned(4)));

// ---------------------------------------------------------------------------
// Pre-pass: tab[(b*NVOX+v)] = 64B entry { half Mi[16], half Mv_b[16] }.
// ---------------------------------------------------------------------------
__global__ __launch_bounds__(256, 2) void build_tab_k(
    const float* __restrict__ vol, const float* __restrict__ tfs,
    const float* __restrict__ tfs_inv, __half* __restrict__ tab)
{
    int v = blockIdx.x * 256 + threadIdx.x;
    int b = blockIdx.y;
    if (v >= NVOX) return;
    float w[JNT];
#pragma unroll
    for (int j = 0; j < JNT; ++j) w[j] = vol[j * NVOX + v];

    float Mi[16], Mv[16];
#pragma unroll
    for (int i = 0; i < 16; ++i) { Mi[i] = 0.f; Mv[i] = 0.f; }
    const float* tb = tfs + (size_t)b * JNT * 16;
#pragma unroll
    for (int j = 0; j < JNT; ++j) {
        float wj = w[j];
#pragma unroll
        for (int i = 0; i < 16; ++i) Mi[i] = fmaf(wj, tfs_inv[j * 16 + i], Mi[i]);
#pragma unroll
        for (int i = 0; i < 16; ++i) Mv[i] = fmaf(wj, tb[j * 16 + i], Mv[i]);
    }
    float h[16];
#pragma unroll
    for (int i = 0; i < 8; ++i)
        h[i] = __builtin_bit_cast(float, __floats2half2_rn(Mi[2*i], Mi[2*i+1]));
#pragma unroll
    for (int i = 0; i < 8; ++i)
        h[8+i] = __builtin_bit_cast(float, __floats2half2_rn(Mv[2*i], Mv[2*i+1]));

    float4* d4 = (float4*)(tab + ((size_t)b * NVOX + v) * 32);
    d4[0] = make_float4(h[0],  h[1],  h[2],  h[3]);
    d4[1] = make_float4(h[4],  h[5],  h[6],  h[7]);
    d4[2] = make_float4(h[8],  h[9],  h[10], h[11]);
    d4[3] = make_float4(h[12], h[13], h[14], h[15]);
}

// Accumulate 8 fp16 values (one float4 of packed half2) into a[0..7].
__device__ __forceinline__ void acc8(float cw, float4 r, float* a)
{
    float rr[4] = {r.x, r.y, r.z, r.w};
#pragma unroll
    for (int kk = 0; kk < 4; ++kk) {
        __half2 h = __builtin_bit_cast(__half2, rr[kk]);
        float2 f = __half22float2(h);
        a[2*kk]     = fmaf(cw, f.x, a[2*kk]);
        a[2*kk + 1] = fmaf(cw, f.y, a[2*kk + 1]);
    }
}

__device__ __forceinline__ void epilogue(
    int b, int n, int N, float x, float y, float z,
    const float* A, const float* Ai,
    const float* __restrict__ shoff, const float* __restrict__ pooff,
    const float* __restrict__ poori,
    float* __restrict__ out_xd, float* __restrict__ out_w)
{
    size_t pid = (size_t)b * N + n;
    size_t p3  = pid * 3;
    size_t n3  = (size_t)n * 3;
    float c0 = Ai[0]*x + Ai[1]*y + Ai[2]*z  + Ai[3];
    float c1 = Ai[4]*x + Ai[5]*y + Ai[6]*z  + Ai[7];
    float c2 = Ai[8]*x + Ai[9]*y + Ai[10]*z + Ai[11];
    float sx = c0 - poori[n3 + 0] + shoff[p3 + 0] + pooff[p3 + 0];
    float sy = c1 - poori[n3 + 1] + shoff[p3 + 1] + pooff[p3 + 1];
    float sz = c2 - poori[n3 + 2] + shoff[p3 + 2] + pooff[p3 + 2];
    out_xd[p3 + 0] = A[0]*sx + A[1]*sy + A[2]*sz  + A[3];
    out_xd[p3 + 1] = A[4]*sx + A[5]*sy + A[6]*sz  + A[7];
    out_xd[p3 + 2] = A[8]*sx + A[9]*sy + A[10]*sz + A[11];

    float4* ow = (float4*)(out_w + pid * 16);
#pragma unroll
    for (int i = 0; i < 4; ++i) {
        float a0 = A[i*4+0], a1 = A[i*4+1], a2 = A[i*4+2], a3 = A[i*4+3];
        float4 r;
        r.x = a0*Ai[0] + a1*Ai[4] + a2*Ai[8]  + a3*Ai[12];
        r.y = a0*Ai[1] + a1*Ai[5] + a2*Ai[9]  + a3*Ai[13];
        r.z = a0*Ai[2] + a1*Ai[6] + a2*Ai[10] + a3*Ai[14];
        r.w = a0*Ai[3] + a1*Ai[7] + a2*Ai[11] + a3*Ai[15];
        ow[i] = r;
    }
}

// ---------------------------------------------------------------------------
// Main kernel: block = 4 waves over the SAME 64-point window; wave w = batch
// w (b = readfirstlane -> SGPR). Per-wave mask partition via ballot +
// ds_permute keeps waves branch-uniform. No LDS, no barriers.
// launch_bounds (256,4): 128-VGPR budget — MUST hold A[16]+Ai[16] without
// spill (R8's (256,8)=32-VGPR cap spilled accumulators -> +430MB scratch).
// ---------------------------------------------------------------------------
template <int B>
__global__ __launch_bounds__(256, 4) void main_k(
    const float* __restrict__ xc,
    const float* __restrict__ shoff,
    const float* __restrict__ pooff,
    const float* __restrict__ tfs,        // [B, J, 16]
    const float* __restrict__ tfs_inv,    // [J, 16]
    const float* __restrict__ poori,      // [N, 3]
    const float* __restrict__ lbsw,       // [N, J]
    const int*   __restrict__ mask,       // [N]
    const __half* __restrict__ tab,       // [B, NVOX, 32 halves]
    const float* __restrict__ offk,
    const float* __restrict__ sck,
    float* __restrict__ out_xd,
    float* __restrict__ out_w,
    int N)
{
    int tx = threadIdx.x;
    int ln = tx & 63;
    int b  = __builtin_amdgcn_readfirstlane(tx >> 6);   // wave-uniform batch
    int base = blockIdx.x * 64;

    // ---- per-wave mask partition (masked slots first), no LDS -------------
    int n0 = base + ln;
    bool mm = (n0 < N) && (mask[n0] != 0);
    unsigned long long bal = __ballot(mm);
    int nm = __popcll(bal);
    unsigned long long below = bal & ((1ull << ln) - 1ull);
    int rb = __popcll(below);
    int pos = mm ? rb : (nm + ln - rb);
    // push own lane id to lane 'pos': perm[pos] = ln
    int slot = __builtin_amdgcn_ds_permute(pos << 2, ln);
    int n = base + slot;
    bool m = (ln < nm);            // masked slots sorted first
    if (n >= N) return;            // tail lives at end of unmasked segment

    size_t p3 = ((size_t)b * N + n) * 3;
    float x = xc[p3], y = xc[p3 + 1], z = xc[p3 + 2];

    float A[16], Ai[16];
#pragma unroll
    for (int i = 0; i < 16; ++i) { A[i] = 0.f; Ai[i] = 0.f; }

    if (m) {
        // ---- masked: matrices wave-uniform -> s_load + v_fma(SGPR) --------
        const float* tb  = tfs + (size_t)b * JNT * 16;
        const float* row = lbsw + (size_t)n * JNT;
#pragma unroll
        for (int jj = 0; jj < 13; ++jj) {
            f4u w4 = *(const f4u*)(row + 4 * jj);
            float wq[4] = {w4.x, w4.y, w4.z, w4.w};
#pragma unroll
            for (int q = 0; q < 4; ++q) {
                int j = 4 * jj + q;
                float wj = wq[q];
#pragma unroll
                for (int i = 0; i < 16; ++i) Ai[i] = fmaf(wj, tfs_inv[j*16+i], Ai[i]);
#pragma unroll
                for (int i = 0; i < 16; ++i) A[i]  = fmaf(wj, tb[j*16+i],      A[i]);
            }
        }
#pragma unroll
        for (int j = 52; j < JNT; ++j) {
            float wj = row[j];
#pragma unroll
            for (int i = 0; i < 16; ++i) Ai[i] = fmaf(wj, tfs_inv[j*16+i], Ai[i]);
#pragma unroll
            for (int i = 0; i < 16; ++i) A[i]  = fmaf(wj, tb[j*16+i],      A[i]);
        }
    } else {
        // ---- unmasked: 8-corner gather of own 64B tab entry ---------------
        float px = (x + offk[0]) * sck[0];
        float py = (y + offk[1]) * sck[1];
        float pz = (z + offk[2]) * sck[2];
        float ix = fminf(fmaxf((px + 1.f) * 0.5f * (VW - 1), 0.f), (float)(VW - 1));
        float iy = fminf(fmaxf((py + 1.f) * 0.5f * (VH - 1), 0.f), (float)(VH - 1));
        float iz = fminf(fmaxf((pz + 1.f) * 0.5f * (VD - 1), 0.f), (float)(VD - 1));
        float fx = floorf(ix), fy = floorf(iy), fz = floorf(iz);
        float wx = ix - fx,    wy = iy - fy,    wz = iz - fz;
        int x0 = (int)fx, y0 = (int)fy, z0 = (int)fz;
        int x1 = min(x0 + 1, VW - 1);
        int y1 = min(y0 + 1, VH - 1);
        int z1 = min(z0 + 1, VD - 1);
        float cwx[2] = {1.f - wx, wx};
        float cwy[2] = {1.f - wy, wy};
        float cwz[2] = {1.f - wz, wz};
        int   xs[2] = {x0, x1}, ys[2] = {y0, y1}, zs[2] = {z0, z1};

        const __half* tbb = tab + (size_t)b * NVOX * 32;
#pragma unroll
        for (int c = 0; c < 8; ++c) {
            int cz = c >> 2, cy = (c >> 1) & 1, cx = c & 1;
            int vox = (zs[cz] * VH + ys[cy]) * VW + xs[cx];
            float cw = cwz[cz] * cwy[cy] * cwx[cx];
            const float4* e = (const float4*)(tbb + (size_t)vox * 32);
            float4 e0 = e[0], e1 = e[1], e2 = e[2], e3 = e[3];
            acc8(cw, e0, Ai);
            acc8(cw, e1, Ai + 8);
            acc8(cw, e2, A);
            acc8(cw, e3, A + 8);
        }
    }

    epilogue(b, n, N, x, y, z, A, Ai, shoff, pooff, poori, out_xd, out_w);
}

// ---------------------------------------------------------------------------
// Fallback (ws too small or B != 4): per-thread direct gather from vol.
// ---------------------------------------------------------------------------
__global__ __launch_bounds__(256) void fb_k(
    const float* __restrict__ xc, const float* __restrict__ shoff,
    const float* __restrict__ pooff, const float* __restrict__ tfs,
    const float* __restrict__ tfs_inv, const float* __restrict__ poori,
    const float* __restrict__ lbsw, const int* __restrict__ mask,
    const float* __restrict__ vol, const float* __restrict__ offk,
    const float* __restrict__ sck, float* __restrict__ out_xd,
    float* __restrict__ out_w, int N)
{
    int n = blockIdx.x * 256 + threadIdx.x;
    int b = blockIdx.y;
    if (n >= N) return;
    size_t p3 = ((size_t)b * N + n) * 3;
    float x = xc[p3], y = xc[p3 + 1], z = xc[p3 + 2];
    float A[16], Ai[16];
#pragma unroll
    for (int i = 0; i < 16; ++i) { A[i] = 0.f; Ai[i] = 0.f; }
    const float* tb = tfs + (size_t)b * JNT * 16;

    if (mask[n] != 0) {
        const float* lp = lbsw + (size_t)n * JNT;
        for (int j = 0; j < JNT; ++j) {
            float wj = lp[j];
#pragma unroll
            for (int i = 0; i < 16; ++i) Ai[i] = fmaf(wj, tfs_inv[j*16+i], Ai[i]);
#pragma unroll
            for (int i = 0; i < 16; ++i) A[i]  = fmaf(wj, tb[j*16+i],      A[i]);
        }
    } else {
        float px = (x + offk[0]) * sck[0];
        float py = (y + offk[1]) * sck[1];
        float pz = (z + offk[2]) * sck[2];
        float ix = fminf(fmaxf((px + 1.f) * 0.5f * (VW - 1), 0.f), (float)(VW - 1));
        float iy = fminf(fmaxf((py + 1.f) * 0.5f * (VH - 1), 0.f), (float)(VH - 1));
        float iz = fminf(fmaxf((pz + 1.f) * 0.5f * (VD - 1), 0.f), (float)(VD - 1));
        float fx = floorf(ix), fy = floorf(iy), fz = floorf(iz);
        float wx = ix - fx, wy = iy - fy, wz = iz - fz;
        int x0 = (int)fx, y0 = (int)fy, z0 = (int)fz;
        int x1 = min(x0 + 1, VW - 1);
        int y1 = min(y0 + 1, VH - 1);
        int z1 = min(z0 + 1, VD - 1);
        float w00 = (1.f - wz) * (1.f - wy), w01 = (1.f - wz) * wy;
        float w10 = wz * (1.f - wy),         w11 = wz * wy;
        int o00 = (z0 * VH + y0) * VW, o01 = (z0 * VH + y1) * VW;
        int o10 = (z1 * VH + y0) * VW, o11 = (z1 * VH + y1) * VW;
        for (int j = 0; j < JNT; ++j) {
            const float* vp = vol + (size_t)j * NVOX;
            float v000 = vp[o00 + x0], v001 = vp[o00 + x1];
            float v010 = vp[o01 + x0], v011 = vp[o01 + x1];
            float v100 = vp[o10 + x0], v101 = vp[o10 + x1];
            float v110 = vp[o11 + x0], v111 = vp[o11 + x1];
            float c0 = w00 * v000 + w01 * v010 + w10 * v100 + w11 * v110;
            float c1 = w00 * v001 + w01 * v011 + w10 * v101 + w11 * v111;
            float wj = c0 + wx * (c1 - c0);
#pragma unroll
            for (int i = 0; i < 16; ++i) Ai[i] = fmaf(wj, tfs_inv[j*16+i], Ai[i]);
#pragma unroll
            for (int i = 0; i < 16; ++i) A[i]  = fmaf(wj, tb[j*16+i],      A[i]);
        }
    }
    epilogue(b, n, N, x, y, z, A, Ai, shoff, pooff, poori, out_xd, out_w);
}

extern "C" void kernel_launch(void* const* d_in, const int* in_sizes, int n_in,
                              void* d_out, int out_size, void* d_ws, size_t ws_size,
                              hipStream_t stream)
{
    const float* xc    = (const float*)d_in[0];
    const float* shoff = (const float*)d_in[1];
    const float* pooff = (const float*)d_in[2];
    const float* tfs   = (const float*)d_in[3];
    const float* tfsi  = (const float*)d_in[4];
    const float* poori = (const float*)d_in[5];
    const float* lbsw  = (const float*)d_in[6];
    const int*   mask  = (const int*)d_in[7];
    const float* vol   = (const float*)d_in[8];
    const float* offk  = (const float*)d_in[9];
    const float* sck   = (const float*)d_in[10];

    int N = in_sizes[5] / 3;          // poseoff_ori [1,N,3]
    int B = in_sizes[0] / (3 * N);    // xc [B,N,3]
    float* out_xd = (float*)d_out;
    float* out_w  = (float*)d_out + (size_t)B * N * 3;

    size_t tab_bytes = (size_t)B * NVOX * 32 * sizeof(__half);  // 16.78 MB
    __half* tab = (__half*)d_ws;

    if (B == 4 && ws_size >= tab_bytes) {
        build_tab_k<<<dim3((NVOX + 255) / 256, 4), dim3(256), 0, stream>>>(
            vol, tfs, tfsi, tab);
        main_k<4><<<dim3((N + 63) / 64), dim3(256), 0, stream>>>(
            xc, shoff, pooff, tfs, tfsi, poori, lbsw, mask, tab,
            offk, sck, out_xd, out_w, N);
    } else {
        fb_k<<<dim3((N + 255) / 256, B), dim3(256), 0, stream>>>(
            xc, shoff, pooff, tfs, tfsi, poori, lbsw, mask, vol, offk, sck,
            out_xd, out_w, N);
    }
}

// Round 5
// 311.823 us; speedup vs baseline: 2.0923x; 1.5135x over previous
//
#include <hip/hip_runtime.h>
#include <hip/hip_fp16.h>

// ForwardDeformer (B=4, N=250000, J=55, vol [55,16,64,64]).
// R1: pre-blend voxel grid with matrices (linearity) -> per-voxel 4x4 mats.
// R5: team=point lane=batch, 111.6us — floor was masked-path DS storm
//     (~280 ds_read_b128/lane) serializing on the CU's single DS pipe.
// R6: block partition + butterfly: VALU 38->30% but DS storm kept, dur flat.
// R7-R9: batch=wave structure (SGPR matrices, no LDS/barriers, per-wave
//     ballot partition, per-thread 64B tab gather) kept SPILLING:
//     empirical launch_bounds mapping on gfx950/ROCm7.2 is
//     (256,8)->32 VGPR (R8: +430MB scratch), (256,4)->64 VGPR (R7/R9:
//     +275MB scratch, FETCH 326/WRITE 351). Body needs ~80-100 VGPRs for
//     A[16]+Ai[16] + unrolled-load live ranges.
// R10: ONE change vs R9: __launch_bounds__(256,2) -> 128-VGPR cap.
//     Expect FETCH ~120MB / WRITE ~80MB (no scratch), dur 55-90us.

#define JNT 55
#define VD  16
#define VH  64
#define VW  64
#define NVOX (VD * VH * VW)   // 65536

typedef float f4u __attribute__((ext_vector_type(4), aligned(4)));

// ---------------------------------------------------------------------------
// Pre-pass: tab[(b*NVOX+v)] = 64B entry { half Mi[16], half Mv_b[16] }.
// ---------------------------------------------------------------------------
__global__ __launch_bounds__(256, 2) void build_tab_k(
    const float* __restrict__ vol, const float* __restrict__ tfs,
    const float* __restrict__ tfs_inv, __half* __restrict__ tab)
{
    int v = blockIdx.x * 256 + threadIdx.x;
    int b = blockIdx.y;
    if (v >= NVOX) return;
    float w[JNT];
#pragma unroll
    for (int j = 0; j < JNT; ++j) w[j] = vol[j * NVOX + v];

    float Mi[16], Mv[16];
#pragma unroll
    for (int i = 0; i < 16; ++i) { Mi[i] = 0.f; Mv[i] = 0.f; }
    const float* tb = tfs + (size_t)b * JNT * 16;
#pragma unroll
    for (int j = 0; j < JNT; ++j) {
        float wj = w[j];
#pragma unroll
        for (int i = 0; i < 16; ++i) Mi[i] = fmaf(wj, tfs_inv[j * 16 + i], Mi[i]);
#pragma unroll
        for (int i = 0; i < 16; ++i) Mv[i] = fmaf(wj, tb[j * 16 + i], Mv[i]);
    }
    float h[16];
#pragma unroll
    for (int i = 0; i < 8; ++i)
        h[i] = __builtin_bit_cast(float, __floats2half2_rn(Mi[2*i], Mi[2*i+1]));
#pragma unroll
    for (int i = 0; i < 8; ++i)
        h[8+i] = __builtin_bit_cast(float, __floats2half2_rn(Mv[2*i], Mv[2*i+1]));

    float4* d4 = (float4*)(tab + ((size_t)b * NVOX + v) * 32);
    d4[0] = make_float4(h[0],  h[1],  h[2],  h[3]);
    d4[1] = make_float4(h[4],  h[5],  h[6],  h[7]);
    d4[2] = make_float4(h[8],  h[9],  h[10], h[11]);
    d4[3] = make_float4(h[12], h[13], h[14], h[15]);
}

// Accumulate 8 fp16 values (one float4 of packed half2) into a[0..7].
__device__ __forceinline__ void acc8(float cw, float4 r, float* a)
{
    float rr[4] = {r.x, r.y, r.z, r.w};
#pragma unroll
    for (int kk = 0; kk < 4; ++kk) {
        __half2 h = __builtin_bit_cast(__half2, rr[kk]);
        float2 f = __half22float2(h);
        a[2*kk]     = fmaf(cw, f.x, a[2*kk]);
        a[2*kk + 1] = fmaf(cw, f.y, a[2*kk + 1]);
    }
}

__device__ __forceinline__ void epilogue(
    int b, int n, int N, float x, float y, float z,
    const float* A, const float* Ai,
    const float* __restrict__ shoff, const float* __restrict__ pooff,
    const float* __restrict__ poori,
    float* __restrict__ out_xd, float* __restrict__ out_w)
{
    size_t pid = (size_t)b * N + n;
    size_t p3  = pid * 3;
    size_t n3  = (size_t)n * 3;
    float c0 = Ai[0]*x + Ai[1]*y + Ai[2]*z  + Ai[3];
    float c1 = Ai[4]*x + Ai[5]*y + Ai[6]*z  + Ai[7];
    float c2 = Ai[8]*x + Ai[9]*y + Ai[10]*z + Ai[11];
    float sx = c0 - poori[n3 + 0] + shoff[p3 + 0] + pooff[p3 + 0];
    float sy = c1 - poori[n3 + 1] + shoff[p3 + 1] + pooff[p3 + 1];
    float sz = c2 - poori[n3 + 2] + shoff[p3 + 2] + pooff[p3 + 2];
    out_xd[p3 + 0] = A[0]*sx + A[1]*sy + A[2]*sz  + A[3];
    out_xd[p3 + 1] = A[4]*sx + A[5]*sy + A[6]*sz  + A[7];
    out_xd[p3 + 2] = A[8]*sx + A[9]*sy + A[10]*sz + A[11];

    float4* ow = (float4*)(out_w + pid * 16);
#pragma unroll
    for (int i = 0; i < 4; ++i) {
        float a0 = A[i*4+0], a1 = A[i*4+1], a2 = A[i*4+2], a3 = A[i*4+3];
        float4 r;
        r.x = a0*Ai[0] + a1*Ai[4] + a2*Ai[8]  + a3*Ai[12];
        r.y = a0*Ai[1] + a1*Ai[5] + a2*Ai[9]  + a3*Ai[13];
        r.z = a0*Ai[2] + a1*Ai[6] + a2*Ai[10] + a3*Ai[14];
        r.w = a0*Ai[3] + a1*Ai[7] + a2*Ai[11] + a3*Ai[15];
        ow[i] = r;
    }
}

// ---------------------------------------------------------------------------
// Main kernel: block = 4 waves over the SAME 64-point window; wave w = batch
// w (b = readfirstlane -> SGPR). Per-wave mask partition via ballot +
// ds_permute keeps waves branch-uniform. No LDS, no barriers.
// launch_bounds (256,2): empirical 128-VGPR cap on this toolchain
// ((256,8)->32, (256,4)->64 both spilled the 32 fp32 accumulators).
// ---------------------------------------------------------------------------
template <int B>
__global__ __launch_bounds__(256, 2) void main_k(
    const float* __restrict__ xc,
    const float* __restrict__ shoff,
    const float* __restrict__ pooff,
    const float* __restrict__ tfs,        // [B, J, 16]
    const float* __restrict__ tfs_inv,    // [J, 16]
    const float* __restrict__ poori,      // [N, 3]
    const float* __restrict__ lbsw,       // [N, J]
    const int*   __restrict__ mask,       // [N]
    const __half* __restrict__ tab,       // [B, NVOX, 32 halves]
    const float* __restrict__ offk,
    const float* __restrict__ sck,
    float* __restrict__ out_xd,
    float* __restrict__ out_w,
    int N)
{
    int tx = threadIdx.x;
    int ln = tx & 63;
    int b  = __builtin_amdgcn_readfirstlane(tx >> 6);   // wave-uniform batch
    int base = blockIdx.x * 64;

    // ---- per-wave mask partition (masked slots first), no LDS -------------
    int n0 = base + ln;
    bool mm = (n0 < N) && (mask[n0] != 0);
    unsigned long long bal = __ballot(mm);
    int nm = __popcll(bal);
    unsigned long long below = bal & ((1ull << ln) - 1ull);
    int rb = __popcll(below);
    int pos = mm ? rb : (nm + ln - rb);
    // push own lane id to lane 'pos': perm[pos] = ln
    int slot = __builtin_amdgcn_ds_permute(pos << 2, ln);
    int n = base + slot;
    bool m = (ln < nm);            // masked slots sorted first
    if (n >= N) return;            // tail lives at end of unmasked segment

    size_t p3 = ((size_t)b * N + n) * 3;
    float x = xc[p3], y = xc[p3 + 1], z = xc[p3 + 2];

    float A[16], Ai[16];
#pragma unroll
    for (int i = 0; i < 16; ++i) { A[i] = 0.f; Ai[i] = 0.f; }

    if (m) {
        // ---- masked: matrices wave-uniform -> s_load + v_fma(SGPR) --------
        const float* tb  = tfs + (size_t)b * JNT * 16;
        const float* row = lbsw + (size_t)n * JNT;
#pragma unroll
        for (int jj = 0; jj < 13; ++jj) {
            f4u w4 = *(const f4u*)(row + 4 * jj);
            float wq[4] = {w4.x, w4.y, w4.z, w4.w};
#pragma unroll
            for (int q = 0; q < 4; ++q) {
                int j = 4 * jj + q;
                float wj = wq[q];
#pragma unroll
                for (int i = 0; i < 16; ++i) Ai[i] = fmaf(wj, tfs_inv[j*16+i], Ai[i]);
#pragma unroll
                for (int i = 0; i < 16; ++i) A[i]  = fmaf(wj, tb[j*16+i],      A[i]);
            }
        }
#pragma unroll
        for (int j = 52; j < JNT; ++j) {
            float wj = row[j];
#pragma unroll
            for (int i = 0; i < 16; ++i) Ai[i] = fmaf(wj, tfs_inv[j*16+i], Ai[i]);
#pragma unroll
            for (int i = 0; i < 16; ++i) A[i]  = fmaf(wj, tb[j*16+i],      A[i]);
        }
    } else {
        // ---- unmasked: 8-corner gather of own 64B tab entry ---------------
        float px = (x + offk[0]) * sck[0];
        float py = (y + offk[1]) * sck[1];
        float pz = (z + offk[2]) * sck[2];
        float ix = fminf(fmaxf((px + 1.f) * 0.5f * (VW - 1), 0.f), (float)(VW - 1));
        float iy = fminf(fmaxf((py + 1.f) * 0.5f * (VH - 1), 0.f), (float)(VH - 1));
        float iz = fminf(fmaxf((pz + 1.f) * 0.5f * (VD - 1), 0.f), (float)(VD - 1));
        float fx = floorf(ix), fy = floorf(iy), fz = floorf(iz);
        float wx = ix - fx,    wy = iy - fy,    wz = iz - fz;
        int x0 = (int)fx, y0 = (int)fy, z0 = (int)fz;
        int x1 = min(x0 + 1, VW - 1);
        int y1 = min(y0 + 1, VH - 1);
        int z1 = min(z0 + 1, VD - 1);
        float cwx[2] = {1.f - wx, wx};
        float cwy[2] = {1.f - wy, wy};
        float cwz[2] = {1.f - wz, wz};
        int   xs[2] = {x0, x1}, ys[2] = {y0, y1}, zs[2] = {z0, z1};

        const __half* tbb = tab + (size_t)b * NVOX * 32;
#pragma unroll
        for (int c = 0; c < 8; ++c) {
            int cz = c >> 2, cy = (c >> 1) & 1, cx = c & 1;
            int vox = (zs[cz] * VH + ys[cy]) * VW + xs[cx];
            float cw = cwz[cz] * cwy[cy] * cwx[cx];
            const float4* e = (const float4*)(tbb + (size_t)vox * 32);
            float4 e0 = e[0], e1 = e[1], e2 = e[2], e3 = e[3];
            acc8(cw, e0, Ai);
            acc8(cw, e1, Ai + 8);
            acc8(cw, e2, A);
            acc8(cw, e3, A + 8);
        }
    }

    epilogue(b, n, N, x, y, z, A, Ai, shoff, pooff, poori, out_xd, out_w);
}

// ---------------------------------------------------------------------------
// Fallback (ws too small or B != 4): per-thread direct gather from vol.
// ---------------------------------------------------------------------------
__global__ __launch_bounds__(256) void fb_k(
    const float* __restrict__ xc, const float* __restrict__ shoff,
    const float* __restrict__ pooff, const float* __restrict__ tfs,
    const float* __restrict__ tfs_inv, const float* __restrict__ poori,
    const float* __restrict__ lbsw, const int* __restrict__ mask,
    const float* __restrict__ vol, const float* __restrict__ offk,
    const float* __restrict__ sck, float* __restrict__ out_xd,
    float* __restrict__ out_w, int N)
{
    int n = blockIdx.x * 256 + threadIdx.x;
    int b = blockIdx.y;
    if (n >= N) return;
    size_t p3 = ((size_t)b * N + n) * 3;
    float x = xc[p3], y = xc[p3 + 1], z = xc[p3 + 2];
    float A[16], Ai[16];
#pragma unroll
    for (int i = 0; i < 16; ++i) { A[i] = 0.f; Ai[i] = 0.f; }
    const float* tb = tfs + (size_t)b * JNT * 16;

    if (mask[n] != 0) {
        const float* lp = lbsw + (size_t)n * JNT;
        for (int j = 0; j < JNT; ++j) {
            float wj = lp[j];
#pragma unroll
            for (int i = 0; i < 16; ++i) Ai[i] = fmaf(wj, tfs_inv[j*16+i], Ai[i]);
#pragma unroll
            for (int i = 0; i < 16; ++i) A[i]  = fmaf(wj, tb[j*16+i],      A[i]);
        }
    } else {
        float px = (x + offk[0]) * sck[0];
        float py = (y + offk[1]) * sck[1];
        float pz = (z + offk[2]) * sck[2];
        float ix = fminf(fmaxf((px + 1.f) * 0.5f * (VW - 1), 0.f), (float)(VW - 1));
        float iy = fminf(fmaxf((py + 1.f) * 0.5f * (VH - 1), 0.f), (float)(VH - 1));
        float iz = fminf(fmaxf((pz + 1.f) * 0.5f * (VD - 1), 0.f), (float)(VD - 1));
        float fx = floorf(ix), fy = floorf(iy), fz = floorf(iz);
        float wx = ix - fx, wy = iy - fy, wz = iz - fz;
        int x0 = (int)fx, y0 = (int)fy, z0 = (int)fz;
        int x1 = min(x0 + 1, VW - 1);
        int y1 = min(y0 + 1, VH - 1);
        int z1 = min(z0 + 1, VD - 1);
        float w00 = (1.f - wz) * (1.f - wy), w01 = (1.f - wz) * wy;
        float w10 = wz * (1.f - wy),         w11 = wz * wy;
        int o00 = (z0 * VH + y0) * VW, o01 = (z0 * VH + y1) * VW;
        int o10 = (z1 * VH + y0) * VW, o11 = (z1 * VH + y1) * VW;
        for (int j = 0; j < JNT; ++j) {
            const float* vp = vol + (size_t)j * NVOX;
            float v000 = vp[o00 + x0], v001 = vp[o00 + x1];
            float v010 = vp[o01 + x0], v011 = vp[o01 + x1];
            float v100 = vp[o10 + x0], v101 = vp[o10 + x1];
            float v110 = vp[o11 + x0], v111 = vp[o11 + x1];
            float c0 = w00 * v000 + w01 * v010 + w10 * v100 + w11 * v110;
            float c1 = w00 * v001 + w01 * v011 + w10 * v101 + w11 * v111;
            float wj = c0 + wx * (c1 - c0);
#pragma unroll
            for (int i = 0; i < 16; ++i) Ai[i] = fmaf(wj, tfs_inv[j*16+i], Ai[i]);
#pragma unroll
            for (int i = 0; i < 16; ++i) A[i]  = fmaf(wj, tb[j*16+i],      A[i]);
        }
    }
    epilogue(b, n, N, x, y, z, A, Ai, shoff, pooff, poori, out_xd, out_w);
}

extern "C" void kernel_launch(void* const* d_in, const int* in_sizes, int n_in,
                              void* d_out, int out_size, void* d_ws, size_t ws_size,
                              hipStream_t stream)
{
    const float* xc    = (const float*)d_in[0];
    const float* shoff = (const float*)d_in[1];
    const float* pooff = (const float*)d_in[2];
    const float* tfs   = (const float*)d_in[3];
    const float* tfsi  = (const float*)d_in[4];
    const float* poori = (const float*)d_in[5];
    const float* lbsw  = (const float*)d_in[6];
    const int*   mask  = (const int*)d_in[7];
    const float* vol   = (const float*)d_in[8];
    const float* offk  = (const float*)d_in[9];
    const float* sck   = (const float*)d_in[10];

    int N = in_sizes[5] / 3;          // poseoff_ori [1,N,3]
    int B = in_sizes[0] / (3 * N);    // xc [B,N,3]
    float* out_xd = (float*)d_out;
    float* out_w  = (float*)d_out + (size_t)B * N * 3;

    size_t tab_bytes = (size_t)B * NVOX * 32 * sizeof(__half);  // 16.78 MB
    __half* tab = (__half*)d_ws;

    if (B == 4 && ws_size >= tab_bytes) {
        build_tab_k<<<dim3((NVOX + 255) / 256, 4), dim3(256), 0, stream>>>(
            vol, tfs, tfsi, tab);
        main_k<4><<<dim3((N + 63) / 64), dim3(256), 0, stream>>>(
            xc, shoff, pooff, tfs, tfsi, poori, lbsw, mask, tab,
            offk, sck, out_xd, out_w, N);
    } else {
        fb_k<<<dim3((N + 255) / 256, B), dim3(256), 0, stream>>>(
            xc, shoff, pooff, tfs, tfsi, poori, lbsw, mask, vol, offk, sck,
            out_xd, out_w, N);
    }
}

// Round 6
// 310.207 us; speedup vs baseline: 2.1032x; 1.0052x over previous
//
#include <hip/hip_runtime.h>
#include <hip/hip_fp16.h>

// ForwardDeformer (B=4, N=250000, J=55, vol [55,16,64,64]).
// R1: pre-blend voxel grid with matrices (linearity) -> per-voxel 4x4 mats.
// R5: team=point lane=batch, 111.6us — masked-path DS storm on 1 DS pipe/CU.
// R7-R10: batch=wave structure (SGPR matrices, no LDS/barriers, per-wave
//     ballot partition, per-thread 64B tab gather). Empirical finding on
//     gfx950/ROCm7.2: __launch_bounds__(256, W) pins waves/EU MIN=MAX=W:
//     VGPR cap = 256/W AND occupancy cap = W waves/SIMD.
//       (256,8): VGPR 32 -> accumulators spill, +430MB scratch, 484us
//       (256,4): VGPR 64 -> spill, +275MB, 294us
//       (256,2): VGPR 108, NO spill, FETCH 113MB/WRITE 74MB = compulsory
//                floor, but occupancy pinned 20% -> latency-bound 130us
// R11: ONE change — drop the waves/EU pin (__launch_bounds__(256) only) on
//     both kernels. Allocator free (~110 VGPR), HW fits ~4 waves/SIMD.
//     Predict occupancy 20->40-50%, main_k 130->70-95us, traffic flat.

#define JNT 55
#define VD  16
#define VH  64
#define VW  64
#define NVOX (VD * VH * VW)   // 65536

typedef float f4u __attribute__((ext_vector_type(4), aligned(4)));

// ---------------------------------------------------------------------------
// Pre-pass: tab[(b*NVOX+v)] = 64B entry { half Mi[16], half Mv_b[16] }.
// ---------------------------------------------------------------------------
__global__ __launch_bounds__(256) void build_tab_k(
    const float* __restrict__ vol, const float* __restrict__ tfs,
    const float* __restrict__ tfs_inv, __half* __restrict__ tab)
{
    int v = blockIdx.x * 256 + threadIdx.x;
    int b = blockIdx.y;
    if (v >= NVOX) return;
    float w[JNT];
#pragma unroll
    for (int j = 0; j < JNT; ++j) w[j] = vol[j * NVOX + v];

    float Mi[16], Mv[16];
#pragma unroll
    for (int i = 0; i < 16; ++i) { Mi[i] = 0.f; Mv[i] = 0.f; }
    const float* tb = tfs + (size_t)b * JNT * 16;
#pragma unroll
    for (int j = 0; j < JNT; ++j) {
        float wj = w[j];
#pragma unroll
        for (int i = 0; i < 16; ++i) Mi[i] = fmaf(wj, tfs_inv[j * 16 + i], Mi[i]);
#pragma unroll
        for (int i = 0; i < 16; ++i) Mv[i] = fmaf(wj, tb[j * 16 + i], Mv[i]);
    }
    float h[16];
#pragma unroll
    for (int i = 0; i < 8; ++i)
        h[i] = __builtin_bit_cast(float, __floats2half2_rn(Mi[2*i], Mi[2*i+1]));
#pragma unroll
    for (int i = 0; i < 8; ++i)
        h[8+i] = __builtin_bit_cast(float, __floats2half2_rn(Mv[2*i], Mv[2*i+1]));

    float4* d4 = (float4*)(tab + ((size_t)b * NVOX + v) * 32);
    d4[0] = make_float4(h[0],  h[1],  h[2],  h[3]);
    d4[1] = make_float4(h[4],  h[5],  h[6],  h[7]);
    d4[2] = make_float4(h[8],  h[9],  h[10], h[11]);
    d4[3] = make_float4(h[12], h[13], h[14], h[15]);
}

// Accumulate 8 fp16 values (one float4 of packed half2) into a[0..7].
__device__ __forceinline__ void acc8(float cw, float4 r, float* a)
{
    float rr[4] = {r.x, r.y, r.z, r.w};
#pragma unroll
    for (int kk = 0; kk < 4; ++kk) {
        __half2 h = __builtin_bit_cast(__half2, rr[kk]);
        float2 f = __half22float2(h);
        a[2*kk]     = fmaf(cw, f.x, a[2*kk]);
        a[2*kk + 1] = fmaf(cw, f.y, a[2*kk + 1]);
    }
}

__device__ __forceinline__ void epilogue(
    int b, int n, int N, float x, float y, float z,
    const float* A, const float* Ai,
    const float* __restrict__ shoff, const float* __restrict__ pooff,
    const float* __restrict__ poori,
    float* __restrict__ out_xd, float* __restrict__ out_w)
{
    size_t pid = (size_t)b * N + n;
    size_t p3  = pid * 3;
    size_t n3  = (size_t)n * 3;
    float c0 = Ai[0]*x + Ai[1]*y + Ai[2]*z  + Ai[3];
    float c1 = Ai[4]*x + Ai[5]*y + Ai[6]*z  + Ai[7];
    float c2 = Ai[8]*x + Ai[9]*y + Ai[10]*z + Ai[11];
    float sx = c0 - poori[n3 + 0] + shoff[p3 + 0] + pooff[p3 + 0];
    float sy = c1 - poori[n3 + 1] + shoff[p3 + 1] + pooff[p3 + 1];
    float sz = c2 - poori[n3 + 2] + shoff[p3 + 2] + pooff[p3 + 2];
    out_xd[p3 + 0] = A[0]*sx + A[1]*sy + A[2]*sz  + A[3];
    out_xd[p3 + 1] = A[4]*sx + A[5]*sy + A[6]*sz  + A[7];
    out_xd[p3 + 2] = A[8]*sx + A[9]*sy + A[10]*sz + A[11];

    float4* ow = (float4*)(out_w + pid * 16);
#pragma unroll
    for (int i = 0; i < 4; ++i) {
        float a0 = A[i*4+0], a1 = A[i*4+1], a2 = A[i*4+2], a3 = A[i*4+3];
        float4 r;
        r.x = a0*Ai[0] + a1*Ai[4] + a2*Ai[8]  + a3*Ai[12];
        r.y = a0*Ai[1] + a1*Ai[5] + a2*Ai[9]  + a3*Ai[13];
        r.z = a0*Ai[2] + a1*Ai[6] + a2*Ai[10] + a3*Ai[14];
        r.w = a0*Ai[3] + a1*Ai[7] + a2*Ai[11] + a3*Ai[15];
        ow[i] = r;
    }
}

// ---------------------------------------------------------------------------
// Main kernel: block = 4 waves over the SAME 64-point window; wave w = batch
// w (b = readfirstlane -> SGPR). Per-wave mask partition via ballot +
// ds_permute keeps waves branch-uniform. No LDS, no barriers.
// __launch_bounds__(256) ONLY: no waves/EU pin (the pin sets min=max on this
// toolchain, capping both VGPRs (256/W, spill) and occupancy (W/SIMD)).
// ---------------------------------------------------------------------------
template <int B>
__global__ __launch_bounds__(256) void main_k(
    const float* __restrict__ xc,
    const float* __restrict__ shoff,
    const float* __restrict__ pooff,
    const float* __restrict__ tfs,        // [B, J, 16]
    const float* __restrict__ tfs_inv,    // [J, 16]
    const float* __restrict__ poori,      // [N, 3]
    const float* __restrict__ lbsw,       // [N, J]
    const int*   __restrict__ mask,       // [N]
    const __half* __restrict__ tab,       // [B, NVOX, 32 halves]
    const float* __restrict__ offk,
    const float* __restrict__ sck,
    float* __restrict__ out_xd,
    float* __restrict__ out_w,
    int N)
{
    int tx = threadIdx.x;
    int ln = tx & 63;
    int b  = __builtin_amdgcn_readfirstlane(tx >> 6);   // wave-uniform batch
    int base = blockIdx.x * 64;

    // ---- per-wave mask partition (masked slots first), no LDS -------------
    int n0 = base + ln;
    bool mm = (n0 < N) && (mask[n0] != 0);
    unsigned long long bal = __ballot(mm);
    int nm = __popcll(bal);
    unsigned long long below = bal & ((1ull << ln) - 1ull);
    int rb = __popcll(below);
    int pos = mm ? rb : (nm + ln - rb);
    // push own lane id to lane 'pos': perm[pos] = ln
    int slot = __builtin_amdgcn_ds_permute(pos << 2, ln);
    int n = base + slot;
    bool m = (ln < nm);            // masked slots sorted first
    if (n >= N) return;            // tail lives at end of unmasked segment

    size_t p3 = ((size_t)b * N + n) * 3;
    float x = xc[p3], y = xc[p3 + 1], z = xc[p3 + 2];

    float A[16], Ai[16];
#pragma unroll
    for (int i = 0; i < 16; ++i) { A[i] = 0.f; Ai[i] = 0.f; }

    if (m) {
        // ---- masked: matrices wave-uniform -> s_load + v_fma(SGPR) --------
        const float* tb  = tfs + (size_t)b * JNT * 16;
        const float* row = lbsw + (size_t)n * JNT;
#pragma unroll
        for (int jj = 0; jj < 13; ++jj) {
            f4u w4 = *(const f4u*)(row + 4 * jj);
            float wq[4] = {w4.x, w4.y, w4.z, w4.w};
#pragma unroll
            for (int q = 0; q < 4; ++q) {
                int j = 4 * jj + q;
                float wj = wq[q];
#pragma unroll
                for (int i = 0; i < 16; ++i) Ai[i] = fmaf(wj, tfs_inv[j*16+i], Ai[i]);
#pragma unroll
                for (int i = 0; i < 16; ++i) A[i]  = fmaf(wj, tb[j*16+i],      A[i]);
            }
        }
#pragma unroll
        for (int j = 52; j < JNT; ++j) {
            float wj = row[j];
#pragma unroll
            for (int i = 0; i < 16; ++i) Ai[i] = fmaf(wj, tfs_inv[j*16+i], Ai[i]);
#pragma unroll
            for (int i = 0; i < 16; ++i) A[i]  = fmaf(wj, tb[j*16+i],      A[i]);
        }
    } else {
        // ---- unmasked: 8-corner gather of own 64B tab entry ---------------
        float px = (x + offk[0]) * sck[0];
        float py = (y + offk[1]) * sck[1];
        float pz = (z + offk[2]) * sck[2];
        float ix = fminf(fmaxf((px + 1.f) * 0.5f * (VW - 1), 0.f), (float)(VW - 1));
        float iy = fminf(fmaxf((py + 1.f) * 0.5f * (VH - 1), 0.f), (float)(VH - 1));
        float iz = fminf(fmaxf((pz + 1.f) * 0.5f * (VD - 1), 0.f), (float)(VD - 1));
        float fx = floorf(ix), fy = floorf(iy), fz = floorf(iz);
        float wx = ix - fx,    wy = iy - fy,    wz = iz - fz;
        int x0 = (int)fx, y0 = (int)fy, z0 = (int)fz;
        int x1 = min(x0 + 1, VW - 1);
        int y1 = min(y0 + 1, VH - 1);
        int z1 = min(z0 + 1, VD - 1);
        float cwx[2] = {1.f - wx, wx};
        float cwy[2] = {1.f - wy, wy};
        float cwz[2] = {1.f - wz, wz};
        int   xs[2] = {x0, x1}, ys[2] = {y0, y1}, zs[2] = {z0, z1};

        const __half* tbb = tab + (size_t)b * NVOX * 32;
#pragma unroll
        for (int c = 0; c < 8; ++c) {
            int cz = c >> 2, cy = (c >> 1) & 1, cx = c & 1;
            int vox = (zs[cz] * VH + ys[cy]) * VW + xs[cx];
            float cw = cwz[cz] * cwy[cy] * cwx[cx];
            const float4* e = (const float4*)(tbb + (size_t)vox * 32);
            float4 e0 = e[0], e1 = e[1], e2 = e[2], e3 = e[3];
            acc8(cw, e0, Ai);
            acc8(cw, e1, Ai + 8);
            acc8(cw, e2, A);
            acc8(cw, e3, A + 8);
        }
    }

    epilogue(b, n, N, x, y, z, A, Ai, shoff, pooff, poori, out_xd, out_w);
}

// ---------------------------------------------------------------------------
// Fallback (ws too small or B != 4): per-thread direct gather from vol.
// ---------------------------------------------------------------------------
__global__ __launch_bounds__(256) void fb_k(
    const float* __restrict__ xc, const float* __restrict__ shoff,
    const float* __restrict__ pooff, const float* __restrict__ tfs,
    const float* __restrict__ tfs_inv, const float* __restrict__ poori,
    const float* __restrict__ lbsw, const int* __restrict__ mask,
    const float* __restrict__ vol, const float* __restrict__ offk,
    const float* __restrict__ sck, float* __restrict__ out_xd,
    float* __restrict__ out_w, int N)
{
    int n = blockIdx.x * 256 + threadIdx.x;
    int b = blockIdx.y;
    if (n >= N) return;
    size_t p3 = ((size_t)b * N + n) * 3;
    float x = xc[p3], y = xc[p3 + 1], z = xc[p3 + 2];
    float A[16], Ai[16];
#pragma unroll
    for (int i = 0; i < 16; ++i) { A[i] = 0.f; Ai[i] = 0.f; }
    const float* tb = tfs + (size_t)b * JNT * 16;

    if (mask[n] != 0) {
        const float* lp = lbsw + (size_t)n * JNT;
        for (int j = 0; j < JNT; ++j) {
            float wj = lp[j];
#pragma unroll
            for (int i = 0; i < 16; ++i) Ai[i] = fmaf(wj, tfs_inv[j*16+i], Ai[i]);
#pragma unroll
            for (int i = 0; i < 16; ++i) A[i]  = fmaf(wj, tb[j*16+i],      A[i]);
        }
    } else {
        float px = (x + offk[0]) * sck[0];
        float py = (y + offk[1]) * sck[1];
        float pz = (z + offk[2]) * sck[2];
        float ix = fminf(fmaxf((px + 1.f) * 0.5f * (VW - 1), 0.f), (float)(VW - 1));
        float iy = fminf(fmaxf((py + 1.f) * 0.5f * (VH - 1), 0.f), (float)(VH - 1));
        float iz = fminf(fmaxf((pz + 1.f) * 0.5f * (VD - 1), 0.f), (float)(VD - 1));
        float fx = floorf(ix), fy = floorf(iy), fz = floorf(iz);
        float wx = ix - fx, wy = iy - fy, wz = iz - fz;
        int x0 = (int)fx, y0 = (int)fy, z0 = (int)fz;
        int x1 = min(x0 + 1, VW - 1);
        int y1 = min(y0 + 1, VH - 1);
        int z1 = min(z0 + 1, VD - 1);
        float w00 = (1.f - wz) * (1.f - wy), w01 = (1.f - wz) * wy;
        float w10 = wz * (1.f - wy),         w11 = wz * wy;
        int o00 = (z0 * VH + y0) * VW, o01 = (z0 * VH + y1) * VW;
        int o10 = (z1 * VH + y0) * VW, o11 = (z1 * VH + y1) * VW;
        for (int j = 0; j < JNT; ++j) {
            const float* vp = vol + (size_t)j * NVOX;
            float v000 = vp[o00 + x0], v001 = vp[o00 + x1];
            float v010 = vp[o01 + x0], v011 = vp[o01 + x1];
            float v100 = vp[o10 + x0], v101 = vp[o10 + x1];
            float v110 = vp[o11 + x0], v111 = vp[o11 + x1];
            float c0 = w00 * v000 + w01 * v010 + w10 * v100 + w11 * v110;
            float c1 = w00 * v001 + w01 * v011 + w10 * v101 + w11 * v111;
            float wj = c0 + wx * (c1 - c0);
#pragma unroll
            for (int i = 0; i < 16; ++i) Ai[i] = fmaf(wj, tfs_inv[j*16+i], Ai[i]);
#pragma unroll
            for (int i = 0; i < 16; ++i) A[i]  = fmaf(wj, tb[j*16+i],      A[i]);
        }
    }
    epilogue(b, n, N, x, y, z, A, Ai, shoff, pooff, poori, out_xd, out_w);
}

extern "C" void kernel_launch(void* const* d_in, const int* in_sizes, int n_in,
                              void* d_out, int out_size, void* d_ws, size_t ws_size,
                              hipStream_t stream)
{
    const float* xc    = (const float*)d_in[0];
    const float* shoff = (const float*)d_in[1];
    const float* pooff = (const float*)d_in[2];
    const float* tfs   = (const float*)d_in[3];
    const float* tfsi  = (const float*)d_in[4];
    const float* poori = (const float*)d_in[5];
    const float* lbsw  = (const float*)d_in[6];
    const int*   mask  = (const int*)d_in[7];
    const float* vol   = (const float*)d_in[8];
    const float* offk  = (const float*)d_in[9];
    const float* sck   = (const float*)d_in[10];

    int N = in_sizes[5] / 3;          // poseoff_ori [1,N,3]
    int B = in_sizes[0] / (3 * N);    // xc [B,N,3]
    float* out_xd = (float*)d_out;
    float* out_w  = (float*)d_out + (size_t)B * N * 3;

    size_t tab_bytes = (size_t)B * NVOX * 32 * sizeof(__half);  // 16.78 MB
    __half* tab = (__half*)d_ws;

    if (B == 4 && ws_size >= tab_bytes) {
        build_tab_k<<<dim3((NVOX + 255) / 256, 4), dim3(256), 0, stream>>>(
            vol, tfs, tfsi, tab);
        main_k<4><<<dim3((N + 63) / 64), dim3(256), 0, stream>>>(
            xc, shoff, pooff, tfs, tfsi, poori, lbsw, mask, tab,
            offk, sck, out_xd, out_w, N);
    } else {
        fb_k<<<dim3((N + 255) / 256, B), dim3(256), 0, stream>>>(
            xc, shoff, pooff, tfs, tfsi, poori, lbsw, mask, vol, offk, sck,
            out_xd, out_w, N);
    }
}

// Round 7
// 277.967 us; speedup vs baseline: 2.3471x; 1.1160x over previous
//
#include <hip/hip_runtime.h>
#include <hip/hip_fp16.h>

// ForwardDeformer (B=4, N=250000, J=55, vol [55,16,64,64]).
// R1: pre-blend voxel grid with matrices (linearity) -> per-voxel 4x4 mats.
// R5: team=point lane=batch, 111.6us (VGPR 40, occ 53%) — DS-storm bound.
// R7-R11: batch=wave structure (SGPR matrices, no LDS/barriers, per-wave
//     ballot partition, per-thread 64B tab gather). Traffic at compulsory
//     floor (FETCH 113MB / WRITE 74MB) but 131us, latency-bound.
//     EMPIRICAL LAW from R5/R8/R9/R10-11: waves/CU ~= 768/VGPR
//     (32->25.6, 40->17, 64->12.8, 108->6.4). At VGPR=108 only ~1.6
//     waves/SIMD -> zero latency hiding; wave lifetime ~33K cy vs ~5K work.
//     Launch-bounds caps (R8/R9) made the allocator SPILL instead (worse).
// R12: REGISTER DIET, same structure, no caps:
//     - masked: #pragma unroll 1 on weight loop (was full unroll = 13 f4u
//       = 52 VGPRs of hoisted weights). Matrices stay s_load (j uniform).
//     - unmasked: corner loop unroll 2, ternary corner selects, <=2 corners
//       (32 VGPR) of loads in flight.
//     Target VGPR 64-84 -> 10-13 waves/CU -> 2x latency hiding.

#define JNT 55
#define VD  16
#define VH  64
#define VW  64
#define NVOX (VD * VH * VW)   // 65536

typedef float f4u __attribute__((ext_vector_type(4), aligned(4)));

// ---------------------------------------------------------------------------
// Pre-pass: tab[(b*NVOX+v)] = 64B entry { half Mi[16], half Mv_b[16] }.
// ---------------------------------------------------------------------------
__global__ __launch_bounds__(256) void build_tab_k(
    const float* __restrict__ vol, const float* __restrict__ tfs,
    const float* __restrict__ tfs_inv, __half* __restrict__ tab)
{
    int v = blockIdx.x * 256 + threadIdx.x;
    int b = blockIdx.y;
    if (v >= NVOX) return;

    float Mi[16], Mv[16];
#pragma unroll
    for (int i = 0; i < 16; ++i) { Mi[i] = 0.f; Mv[i] = 0.f; }
    const float* tb = tfs + (size_t)b * JNT * 16;
#pragma unroll 1
    for (int j = 0; j < JNT; ++j) {
        float wj = vol[j * NVOX + v];
#pragma unroll
        for (int i = 0; i < 16; ++i) Mi[i] = fmaf(wj, tfs_inv[j * 16 + i], Mi[i]);
#pragma unroll
        for (int i = 0; i < 16; ++i) Mv[i] = fmaf(wj, tb[j * 16 + i], Mv[i]);
    }
    float h[16];
#pragma unroll
    for (int i = 0; i < 8; ++i)
        h[i] = __builtin_bit_cast(float, __floats2half2_rn(Mi[2*i], Mi[2*i+1]));
#pragma unroll
    for (int i = 0; i < 8; ++i)
        h[8+i] = __builtin_bit_cast(float, __floats2half2_rn(Mv[2*i], Mv[2*i+1]));

    float4* d4 = (float4*)(tab + ((size_t)b * NVOX + v) * 32);
    d4[0] = make_float4(h[0],  h[1],  h[2],  h[3]);
    d4[1] = make_float4(h[4],  h[5],  h[6],  h[7]);
    d4[2] = make_float4(h[8],  h[9],  h[10], h[11]);
    d4[3] = make_float4(h[12], h[13], h[14], h[15]);
}

// Accumulate 8 fp16 values (one float4 of packed half2) into a[0..7].
__device__ __forceinline__ void acc8(float cw, float4 r, float* a)
{
    float rr[4] = {r.x, r.y, r.z, r.w};
#pragma unroll
    for (int kk = 0; kk < 4; ++kk) {
        __half2 h = __builtin_bit_cast(__half2, rr[kk]);
        float2 f = __half22float2(h);
        a[2*kk]     = fmaf(cw, f.x, a[2*kk]);
        a[2*kk + 1] = fmaf(cw, f.y, a[2*kk + 1]);
    }
}

__device__ __forceinline__ void epilogue(
    int b, int n, int N, float x, float y, float z,
    const float* A, const float* Ai,
    const float* __restrict__ shoff, const float* __restrict__ pooff,
    const float* __restrict__ poori,
    float* __restrict__ out_xd, float* __restrict__ out_w)
{
    size_t pid = (size_t)b * N + n;
    size_t p3  = pid * 3;
    size_t n3  = (size_t)n * 3;
    float c0 = Ai[0]*x + Ai[1]*y + Ai[2]*z  + Ai[3];
    float c1 = Ai[4]*x + Ai[5]*y + Ai[6]*z  + Ai[7];
    float c2 = Ai[8]*x + Ai[9]*y + Ai[10]*z + Ai[11];
    float sx = c0 - poori[n3 + 0] + shoff[p3 + 0] + pooff[p3 + 0];
    float sy = c1 - poori[n3 + 1] + shoff[p3 + 1] + pooff[p3 + 1];
    float sz = c2 - poori[n3 + 2] + shoff[p3 + 2] + pooff[p3 + 2];
    out_xd[p3 + 0] = A[0]*sx + A[1]*sy + A[2]*sz  + A[3];
    out_xd[p3 + 1] = A[4]*sx + A[5]*sy + A[6]*sz  + A[7];
    out_xd[p3 + 2] = A[8]*sx + A[9]*sy + A[10]*sz + A[11];

    float4* ow = (float4*)(out_w + pid * 16);
#pragma unroll
    for (int i = 0; i < 4; ++i) {
        float a0 = A[i*4+0], a1 = A[i*4+1], a2 = A[i*4+2], a3 = A[i*4+3];
        float4 r;
        r.x = a0*Ai[0] + a1*Ai[4] + a2*Ai[8]  + a3*Ai[12];
        r.y = a0*Ai[1] + a1*Ai[5] + a2*Ai[9]  + a3*Ai[13];
        r.z = a0*Ai[2] + a1*Ai[6] + a2*Ai[10] + a3*Ai[14];
        r.w = a0*Ai[3] + a1*Ai[7] + a2*Ai[11] + a3*Ai[15];
        ow[i] = r;
    }
}

// ---------------------------------------------------------------------------
// Main kernel: block = 4 waves over the SAME 64-point window; wave w = batch
// w (b = readfirstlane -> SGPR). Per-wave mask partition via ballot +
// ds_permute keeps waves branch-uniform. No LDS, no barriers, no VGPR caps
// (caps -> spill). Register diet targets VGPR<=84 for >=10 waves/CU.
// ---------------------------------------------------------------------------
template <int B>
__global__ __launch_bounds__(256) void main_k(
    const float* __restrict__ xc,
    const float* __restrict__ shoff,
    const float* __restrict__ pooff,
    const float* __restrict__ tfs,        // [B, J, 16]
    const float* __restrict__ tfs_inv,    // [J, 16]
    const float* __restrict__ poori,      // [N, 3]
    const float* __restrict__ lbsw,       // [N, J]
    const int*   __restrict__ mask,       // [N]
    const __half* __restrict__ tab,       // [B, NVOX, 32 halves]
    const float* __restrict__ offk,
    const float* __restrict__ sck,
    float* __restrict__ out_xd,
    float* __restrict__ out_w,
    int N)
{
    int tx = threadIdx.x;
    int ln = tx & 63;
    int b  = __builtin_amdgcn_readfirstlane(tx >> 6);   // wave-uniform batch
    int base = blockIdx.x * 64;

    // ---- per-wave mask partition (masked slots first), no LDS -------------
    int n0 = base + ln;
    bool mm = (n0 < N) && (mask[n0] != 0);
    unsigned long long bal = __ballot(mm);
    int nm = __popcll(bal);
    unsigned long long below = bal & ((1ull << ln) - 1ull);
    int rb = __popcll(below);
    int pos = mm ? rb : (nm + ln - rb);
    // push own lane id to lane 'pos': perm[pos] = ln
    int slot = __builtin_amdgcn_ds_permute(pos << 2, ln);
    int n = base + slot;
    bool m = (ln < nm);            // masked slots sorted first
    if (n >= N) return;            // tail lives at end of unmasked segment

    size_t p3 = ((size_t)b * N + n) * 3;
    float x = xc[p3], y = xc[p3 + 1], z = xc[p3 + 2];

    float A[16], Ai[16];
#pragma unroll
    for (int i = 0; i < 16; ++i) { A[i] = 0.f; Ai[i] = 0.f; }

    if (m) {
        // ---- masked: matrices wave-uniform -> s_load + v_fma(SGPR) --------
        // unroll 1: only ONE w4 vector live (full unroll hoisted 52 VGPRs).
        const float* tb  = tfs + (size_t)b * JNT * 16;
        const float* row = lbsw + (size_t)n * JNT;
#pragma unroll 1
        for (int jj = 0; jj < 13; ++jj) {
            f4u w4 = *(const f4u*)(row + 4 * jj);
            float wq[4] = {w4.x, w4.y, w4.z, w4.w};
#pragma unroll
            for (int q = 0; q < 4; ++q) {
                int j = 4 * jj + q;
                float wj = wq[q];
#pragma unroll
                for (int i = 0; i < 16; ++i) Ai[i] = fmaf(wj, tfs_inv[j*16+i], Ai[i]);
#pragma unroll
                for (int i = 0; i < 16; ++i) A[i]  = fmaf(wj, tb[j*16+i],      A[i]);
            }
        }
#pragma unroll 1
        for (int j = 52; j < JNT; ++j) {
            float wj = row[j];
#pragma unroll
            for (int i = 0; i < 16; ++i) Ai[i] = fmaf(wj, tfs_inv[j*16+i], Ai[i]);
#pragma unroll
            for (int i = 0; i < 16; ++i) A[i]  = fmaf(wj, tb[j*16+i],      A[i]);
        }
    } else {
        // ---- unmasked: 8-corner gather of own 64B tab entry ---------------
        // unroll 2: <=2 corners (32B each) of load data in flight.
        float px = (x + offk[0]) * sck[0];
        float py = (y + offk[1]) * sck[1];
        float pz = (z + offk[2]) * sck[2];
        float ix = fminf(fmaxf((px + 1.f) * 0.5f * (VW - 1), 0.f), (float)(VW - 1));
        float iy = fminf(fmaxf((py + 1.f) * 0.5f * (VH - 1), 0.f), (float)(VH - 1));
        float iz = fminf(fmaxf((pz + 1.f) * 0.5f * (VD - 1), 0.f), (float)(VD - 1));
        float fx = floorf(ix), fy = floorf(iy), fz = floorf(iz);
        float wx = ix - fx,    wy = iy - fy,    wz = iz - fz;
        int x0 = (int)fx, y0 = (int)fy, z0 = (int)fz;
        int x1 = min(x0 + 1, VW - 1);
        int y1 = min(y0 + 1, VH - 1);
        int z1 = min(z0 + 1, VD - 1);

        const __half* tbb = tab + (size_t)b * NVOX * 32;
#pragma unroll 2
        for (int c = 0; c < 8; ++c) {
            int zc = (c & 4) ? z1 : z0;
            int yc = (c & 2) ? y1 : y0;
            int xcc = (c & 1) ? x1 : x0;
            float cw = ((c & 4) ? wz : 1.f - wz)
                     * ((c & 2) ? wy : 1.f - wy)
                     * ((c & 1) ? wx : 1.f - wx);
            int vox = (zc * VH + yc) * VW + xcc;
            const float4* e = (const float4*)(tbb + (size_t)vox * 32);
            float4 e0 = e[0], e1 = e[1], e2 = e[2], e3 = e[3];
            acc8(cw, e0, Ai);
            acc8(cw, e1, Ai + 8);
            acc8(cw, e2, A);
            acc8(cw, e3, A + 8);
        }
    }

    epilogue(b, n, N, x, y, z, A, Ai, shoff, pooff, poori, out_xd, out_w);
}

// ---------------------------------------------------------------------------
// Fallback (ws too small or B != 4): per-thread direct gather from vol.
// ---------------------------------------------------------------------------
__global__ __launch_bounds__(256) void fb_k(
    const float* __restrict__ xc, const float* __restrict__ shoff,
    const float* __restrict__ pooff, const float* __restrict__ tfs,
    const float* __restrict__ tfs_inv, const float* __restrict__ poori,
    const float* __restrict__ lbsw, const int* __restrict__ mask,
    const float* __restrict__ vol, const float* __restrict__ offk,
    const float* __restrict__ sck, float* __restrict__ out_xd,
    float* __restrict__ out_w, int N)
{
    int n = blockIdx.x * 256 + threadIdx.x;
    int b = blockIdx.y;
    if (n >= N) return;
    size_t p3 = ((size_t)b * N + n) * 3;
    float x = xc[p3], y = xc[p3 + 1], z = xc[p3 + 2];
    float A[16], Ai[16];
#pragma unroll
    for (int i = 0; i < 16; ++i) { A[i] = 0.f; Ai[i] = 0.f; }
    const float* tb = tfs + (size_t)b * JNT * 16;

    if (mask[n] != 0) {
        const float* lp = lbsw + (size_t)n * JNT;
#pragma unroll 1
        for (int j = 0; j < JNT; ++j) {
            float wj = lp[j];
#pragma unroll
            for (int i = 0; i < 16; ++i) Ai[i] = fmaf(wj, tfs_inv[j*16+i], Ai[i]);
#pragma unroll
            for (int i = 0; i < 16; ++i) A[i]  = fmaf(wj, tb[j*16+i],      A[i]);
        }
    } else {
        float px = (x + offk[0]) * sck[0];
        float py = (y + offk[1]) * sck[1];
        float pz = (z + offk[2]) * sck[2];
        float ix = fminf(fmaxf((px + 1.f) * 0.5f * (VW - 1), 0.f), (float)(VW - 1));
        float iy = fminf(fmaxf((py + 1.f) * 0.5f * (VH - 1), 0.f), (float)(VH - 1));
        float iz = fminf(fmaxf((pz + 1.f) * 0.5f * (VD - 1), 0.f), (float)(VD - 1));
        float fx = floorf(ix), fy = floorf(iy), fz = floorf(iz);
        float wx = ix - fx, wy = iy - fy, wz = iz - fz;
        int x0 = (int)fx, y0 = (int)fy, z0 = (int)fz;
        int x1 = min(x0 + 1, VW - 1);
        int y1 = min(y0 + 1, VH - 1);
        int z1 = min(z0 + 1, VD - 1);
        float w00 = (1.f - wz) * (1.f - wy), w01 = (1.f - wz) * wy;
        float w10 = wz * (1.f - wy),         w11 = wz * wy;
        int o00 = (z0 * VH + y0) * VW, o01 = (z0 * VH + y1) * VW;
        int o10 = (z1 * VH + y0) * VW, o11 = (z1 * VH + y1) * VW;
#pragma unroll 1
        for (int j = 0; j < JNT; ++j) {
            const float* vp = vol + (size_t)j * NVOX;
            float v000 = vp[o00 + x0], v001 = vp[o00 + x1];
            float v010 = vp[o01 + x0], v011 = vp[o01 + x1];
            float v100 = vp[o10 + x0], v101 = vp[o10 + x1];
            float v110 = vp[o11 + x0], v111 = vp[o11 + x1];
            float c0 = w00 * v000 + w01 * v010 + w10 * v100 + w11 * v110;
            float c1 = w00 * v001 + w01 * v011 + w10 * v101 + w11 * v111;
            float wj = c0 + wx * (c1 - c0);
#pragma unroll
            for (int i = 0; i < 16; ++i) Ai[i] = fmaf(wj, tfs_inv[j*16+i], Ai[i]);
#pragma unroll
            for (int i = 0; i < 16; ++i) A[i]  = fmaf(wj, tb[j*16+i],      A[i]);
        }
    }
    epilogue(b, n, N, x, y, z, A, Ai, shoff, pooff, poori, out_xd, out_w);
}

extern "C" void kernel_launch(void* const* d_in, const int* in_sizes, int n_in,
                              void* d_out, int out_size, void* d_ws, size_t ws_size,
                              hipStream_t stream)
{
    const float* xc    = (const float*)d_in[0];
    const float* shoff = (const float*)d_in[1];
    const float* pooff = (const float*)d_in[2];
    const float* tfs   = (const float*)d_in[3];
    const float* tfsi  = (const float*)d_in[4];
    const float* poori = (const float*)d_in[5];
    const float* lbsw  = (const float*)d_in[6];
    const int*   mask  = (const int*)d_in[7];
    const float* vol   = (const float*)d_in[8];
    const float* offk  = (const float*)d_in[9];
    const float* sck   = (const float*)d_in[10];

    int N = in_sizes[5] / 3;          // poseoff_ori [1,N,3]
    int B = in_sizes[0] / (3 * N);    // xc [B,N,3]
    float* out_xd = (float*)d_out;
    float* out_w  = (float*)d_out + (size_t)B * N * 3;

    size_t tab_bytes = (size_t)B * NVOX * 32 * sizeof(__half);  // 16.78 MB
    __half* tab = (__half*)d_ws;

    if (B == 4 && ws_size >= tab_bytes) {
        build_tab_k<<<dim3((NVOX + 255) / 256, 4), dim3(256), 0, stream>>>(
            vol, tfs, tfsi, tab);
        main_k<4><<<dim3((N + 63) / 64), dim3(256), 0, stream>>>(
            xc, shoff, pooff, tfs, tfsi, poori, lbsw, mask, tab,
            offk, sck, out_xd, out_w, N);
    } else {
        fb_k<<<dim3((N + 255) / 256, B), dim3(256), 0, stream>>>(
            xc, shoff, pooff, tfs, tfsi, poori, lbsw, mask, vol, offk, sck,
            out_xd, out_w, N);
    }
}